// Round 3
// baseline (380.125 us; speedup 1.0000x reference)
//
#include <hip/hip_runtime.h>

#define WW 1024
#define HH 1024
#define NIMG 2
#define NCH 8
#define HWSZ (HH * WW)
#define CHW (NCH * HWSZ)
#define NBLK_MASK 2048
#define NBLK_MAIN 4096
// ws u32 layout: [0..2047] block mins, [2048..4095] block maxs,
// [4096] sum, [4097] cnt, [4098] ticket,
// dv16 (packed unorm16 mask diff) at 4352, u8 qt records at WS_QT.
#define WS_SUM 4096
#define WS_CNT 4097
#define WS_TKT 4098
#define WS_DV16 4352
#define WS_QT (4352 + HWSZ)
#define RECU4 320   // uint4 per (n,row,half) record: [p0 136][p1 136][pad 48]

typedef unsigned int uint;

__device__ __forceinline__ uint pknorm(float a, float b) {
    uint d;
    asm("v_cvt_pknorm_u16_f32 %0, %1, %2" : "=v"(d) : "v"(a), "v"(b));
    return d;
}
__device__ __forceinline__ uint sadu8(uint a, uint b, uint c) {
    uint d;
    asm("v_sad_u8 %0, %1, %2, %3" : "=v"(d) : "v"(a), "v"(b), "v"(c));
    return d;
}
__device__ __forceinline__ uint q8(float x) {
    return (uint)__float2int_rn(x * 255.f);
}
__device__ __forceinline__ int reflect_idx(int t) {
    if (t < 0) t = -t;
    if (t > HH - 1) t = 2 * (HH - 1) - t;
    return t;
}
// padded granule (0..135) -> E/O slot (E first, then O)
__device__ __forceinline__ int gp2slot(int gp) {
    return (gp & 1) ? (68 + (gp >> 1)) : (gp >> 1);
}

// Pass 0: quantize tgt to u8 (4 ch per u32); per (n,row,half) a 320-uint4 record
// [p0: E68|O68][p1: E68|O68][pad], reflected col-halos baked in. (verified, unchanged)
__global__ __launch_bounds__(256) void k_quant(const float* __restrict__ tgt,
                                               uint4* __restrict__ qt4) {
    int b = blockIdx.x;            // (n*2+p)*1024 + row
    int t = threadIdx.x;           // image granule (4 px)
    int row = b & 1023;
    int np = b >> 10;
    int n = np >> 1, p = np & 1;
    const float* c0 = tgt + (size_t)(n * NCH + 4 * p) * HWSZ + (size_t)row * WW;

    float4 v0 = *(const float4*)(c0 + 4 * t);
    float4 v1 = *(const float4*)(c0 + HWSZ + 4 * t);
    float4 v2 = *(const float4*)(c0 + 2 * HWSZ + 4 * t);
    float4 v3 = *(const float4*)(c0 + 3 * HWSZ + 4 * t);
    uint4 u;
    u.x = q8(v0.x) | (q8(v1.x) << 8) | (q8(v2.x) << 16) | (q8(v3.x) << 24);
    u.y = q8(v0.y) | (q8(v1.y) << 8) | (q8(v2.y) << 16) | (q8(v3.y) << 24);
    u.z = q8(v0.z) | (q8(v1.z) << 8) | (q8(v2.z) << 16) | (q8(v3.z) << 24);
    u.w = q8(v0.w) | (q8(v1.w) << 8) | (q8(v2.w) << 16) | (q8(v3.w) << 24);

    size_t rb = ((size_t)((n << 10) + row)) * 2;
    int h1 = t >> 7;
    int gp = (t & 127) + 4;        // 4..131 within own half
    qt4[(rb + h1) * RECU4 + p * 136 + gp2slot(gp)] = u;
    // interior overlap granules (appear in the other half's halo region)
    if (t >= 124 && t < 128)
        qt4[(rb + 1) * RECU4 + p * 136 + gp2slot(t - 124)] = u;
    if (t >= 128 && t < 132)
        qt4[(rb + 0) * RECU4 + p * 136 + gp2slot(t - 128 + 132)] = u;
    // reflected edge halos: 32 scalar u32 (one px each)
    if (t < 32) {
        int which = t >> 4, m = t & 15;
        int pc = which ? (528 + m) : m;          // padded col
        int j = which ? (1022 - m) : (16 - m);   // reflected image col
        uint val = q8(c0[j]) | (q8(c0[j + HWSZ]) << 8) |
                   (q8(c0[j + 2 * HWSZ]) << 16) | (q8(c0[j + 3 * HWSZ]) << 24);
        uint* recU = (uint*)(qt4 + (rb + which) * RECU4);
        recU[p * 544 + gp2slot(pc >> 2) * 4 + (pc & 3)] = val;
    }
}

// Pass 1: mask diff -> packed unorm16; per-block min/max. (verified, unchanged)
__global__ __launch_bounds__(256) void k_mask(const float* __restrict__ msO,
                                              const float* __restrict__ pan,
                                              float* __restrict__ wsF,
                                              uint* __restrict__ dv16) {
    int b = blockIdx.x;
    int gid = b * 256 + threadIdx.x;
    int base = gid * 4;
    int n = base >> 20;
    int hw = base & (HWSZ - 1);
    const float* po = msO + (size_t)n * CHW + hw;
    float sx = 0.f, sy = 0.f, sz = 0.f, sw = 0.f;
#pragma unroll
    for (int c = 0; c < NCH; ++c) {
        float4 v = *(const float4*)(po + c * HWSZ);
        sx += v.x; sy += v.y; sz += v.z; sw += v.w;
    }
    float4 pv = *(const float4*)(pan + (size_t)n * HWSZ + hw);
    float4 d;
    d.x = fabsf(sx * 0.125f - pv.x);
    d.y = fabsf(sy * 0.125f - pv.y);
    d.z = fabsf(sz * 0.125f - pv.z);
    d.w = fabsf(sw * 0.125f - pv.w);
    uint2 dpk;
    dpk.x = pknorm(d.x, d.y);
    dpk.y = pknorm(d.z, d.w);
    *(uint2*)(dv16 + (base >> 1)) = dpk;

    float m = fminf(fminf(d.x, d.y), fminf(d.z, d.w));
    float M = fmaxf(fmaxf(d.x, d.y), fmaxf(d.z, d.w));
#pragma unroll
    for (int off = 32; off > 0; off >>= 1) {
        m = fminf(m, __shfl_down(m, off));
        M = fmaxf(M, __shfl_down(M, off));
    }
    __shared__ float sm[4], sM[4];
    int wid = threadIdx.x >> 6, lane = threadIdx.x & 63;
    if (lane == 0) { sm[wid] = m; sM[wid] = M; }
    __syncthreads();
    if (threadIdx.x == 0) {
        wsF[b] = fminf(fminf(sm[0], sm[1]), fminf(sm[2], sm[3]));
        wsF[2048 + b] = fmaxf(fmaxf(sM[0], sM[1]), fmaxf(sM[2], sM[3]));
        if (b == 0) {
            wsF[WS_SUM] = 0.f;
            wsF[WS_CNT] = 0.f;
            ((unsigned*)wsF)[WS_TKT] = 0u;
        }
    }
}

// Pass 2: 1-wave block = ONE output row half. No LDS: windows read directly from
// qt4 (L2-resident per XCD band). amdgpu_waves_per_eu(3,3) pins the occupancy
// target: without it the backend targets 8 waves/SIMD and caps VGPRs at 64,
// spilling the 80-VGPR window burst (R2: VGPR=64, 203us). Cap 512/3=170 VGPRs
// fits the ~130-reg working set (R0 evidence: 132 VGPRs, no spill) at 3 waves/SIMD.
__global__ __launch_bounds__(64)
__attribute__((amdgpu_waves_per_eu(3, 3)))
void k_main(const float* __restrict__ ms,
            const uint4* __restrict__ qt4,
            float* __restrict__ wsF,
            const uint* __restrict__ dv16,
            float* __restrict__ out) {
    const int t = threadIdx.x;        // 0..63
    const int b = blockIdx.x;         // 0..4095
    const int xcd = b & 7;
    const int q = b >> 3;             // 0..511
    const int rowb = q & 127;         // consecutive blocks on an XCD = adjacent rows
    const int hb = (q >> 7) & 1;
    const int n = q >> 8;
    const int oh = xcd * 128 + rowb;
    const int w0 = hb * 512 + 8 * t;

    // ---- mask min/max ----
    float lmin = 1.0e38f, lmax = -1.0e38f;
#pragma unroll
    for (int k = 0; k < 8; ++k) {
        float4 v = ((const float4*)wsF)[k * 64 + t];
        float4 x = ((const float4*)(wsF + 2048))[k * 64 + t];
        lmin = fminf(lmin, fminf(fminf(v.x, v.y), fminf(v.z, v.w)));
        lmax = fmaxf(lmax, fmaxf(fmaxf(x.x, x.y), fmaxf(x.z, x.w)));
    }

    // ---- ms fragment: 8 px x 8 ch, issued early ----
    const float* msBase = ms + (size_t)n * CHW + (size_t)oh * WW + w0;
    float4 A[2][4][2];
#pragma unroll
    for (int p = 0; p < 2; ++p)
#pragma unroll
        for (int cc = 0; cc < 4; ++cc) {
            A[p][cc][0] = *(const float4*)(msBase + (size_t)(4 * p + cc) * HWSZ);
            A[p][cc][1] = *(const float4*)(msBase + (size_t)(4 * p + cc) * HWSZ + 4);
        }
    uint4 dq = *(const uint4*)(dv16 + (((size_t)n * HWSZ + (size_t)oh * WW + w0) >> 1));

#pragma unroll
    for (int off = 32; off > 0; off >>= 1) {
        lmin = fminf(lmin, __shfl_xor(lmin, off));
        lmax = fmaxf(lmax, __shfl_xor(lmax, off));
    }
    const float thresh = lmin + (lmax - lmin) * (10.0f / 255.0f);
    const float inv16 = 1.0f / 65535.0f;
    const float inv8 = 1.0f / 255.0f;

    // pack ms fragment to u8
    uint msq[2][8];
#pragma unroll
    for (int p = 0; p < 2; ++p) {
#pragma unroll
        for (int half = 0; half < 2; ++half) {
            float4 c0 = A[p][0][half], c1 = A[p][1][half],
                   c2 = A[p][2][half], c3 = A[p][3][half];
            msq[p][4 * half + 0] = q8(c0.x) | (q8(c1.x) << 8) | (q8(c2.x) << 16) | (q8(c3.x) << 24);
            msq[p][4 * half + 1] = q8(c0.y) | (q8(c1.y) << 8) | (q8(c2.y) << 16) | (q8(c3.y) << 24);
            msq[p][4 * half + 2] = q8(c0.z) | (q8(c1.z) << 8) | (q8(c2.z) << 16) | (q8(c3.z) << 24);
            msq[p][4 * half + 3] = q8(c0.w) | (q8(c1.w) << 8) | (q8(c2.w) << 16) | (q8(c3.w) << 24);
        }
    }

    uint minv[8];
#pragma unroll
    for (int p = 0; p < 8; ++p) minv[p] = 0xffffffffu;

    const size_t nBase = ((size_t)n << 10);
#pragma unroll 1
    for (int di = 0; di < 9; ++di) {
        int rr = reflect_idx(oh + 4 * (di - 4));
        // per-lane base: record + 16*t bytes; all window offsets are immediates
        const uint* recU = (const uint*)(qt4 + ((nBase + rr) * 2 + hb) * RECU4) + 4 * t;
        uint4 winE[2][5], winO[2][5];
#pragma unroll
        for (int p = 0; p < 2; ++p)
#pragma unroll
            for (int qq = 0; qq < 5; ++qq) {
                winE[p][qq] = *(const uint4*)(recU + p * 544 + 4 * qq);
                winO[p][qq] = *(const uint4*)(recU + p * 544 + 272 + 4 * qq);
            }
        uint acc[8];
#pragma unroll
        for (int dj = 0; dj < 9; ++dj) {
#pragma unroll
            for (int p = 0; p < 8; ++p) acc[p] = 0;
#pragma unroll
            for (int p = 0; p < 2; ++p) {
                uint4 lo = (dj & 1) ? winO[p][(dj - 1) >> 1] : winE[p][dj >> 1];
                uint4 hi = (dj & 1) ? winE[p][(dj + 1) >> 1] : winO[p][dj >> 1];
                acc[0] = sadu8(msq[p][0], lo.x, acc[0]);
                acc[1] = sadu8(msq[p][1], lo.y, acc[1]);
                acc[2] = sadu8(msq[p][2], lo.z, acc[2]);
                acc[3] = sadu8(msq[p][3], lo.w, acc[3]);
                acc[4] = sadu8(msq[p][4], hi.x, acc[4]);
                acc[5] = sadu8(msq[p][5], hi.y, acc[5]);
                acc[6] = sadu8(msq[p][6], hi.z, acc[6]);
                acc[7] = sadu8(msq[p][7], hi.w, acc[7]);
            }
#pragma unroll
            for (int p = 0; p < 8; ++p) minv[p] = min(minv[p], acc[p]);
        }
    }

    // masked accumulate for this output row
    float lsum = 0.f, lcnt = 0.f;
    uint dw[4] = {dq.x, dq.y, dq.z, dq.w};
#pragma unroll
    for (int p = 0; p < 4; ++p) {
        float d0 = (float)(dw[p] & 0xffffu) * inv16;
        float d1 = (float)(dw[p] >> 16) * inv16;
        if (d0 > thresh) { lsum += (float)minv[2 * p] * inv8; lcnt += 1.f; }
        if (d1 > thresh) { lsum += (float)minv[2 * p + 1] * inv8; lcnt += 1.f; }
    }

#pragma unroll
    for (int off = 32; off > 0; off >>= 1) {
        lsum += __shfl_down(lsum, off);
        lcnt += __shfl_down(lcnt, off);
    }
    if (t == 0) {
        atomicAdd(&wsF[WS_SUM], lsum);
        atomicAdd(&wsF[WS_CNT], lcnt);
        __threadfence();
        unsigned tk = atomicAdd((unsigned*)&wsF[WS_TKT], 1u);
        if (tk == NBLK_MAIN - 1) {
            float s = atomicAdd(&wsF[WS_SUM], 0.f);
            float c = atomicAdd(&wsF[WS_CNT], 0.f);
            out[0] = (c > 0.f) ? (s / fmaxf(c, 1.f)) : 0.f;
        }
    }
}

extern "C" void kernel_launch(void* const* d_in, const int* in_sizes, int n_in,
                              void* d_out, int out_size, void* d_ws, size_t ws_size,
                              hipStream_t stream) {
    const float* ms  = (const float*)d_in[0];
    const float* tgt = (const float*)d_in[1];
    const float* msO = (const float*)d_in[2];
    const float* pan = (const float*)d_in[3];
    float* out = (float*)d_out;
    float* wsF = (float*)d_ws;
    uint* dv16 = (uint*)d_ws + WS_DV16;
    uint4* qt4 = (uint4*)((uint*)d_ws + WS_QT);

    k_quant<<<NIMG * 2 * 1024, 256, 0, stream>>>(tgt, qt4);
    k_mask<<<NBLK_MASK, 256, 0, stream>>>(msO, pan, wsF, dv16);
    k_main<<<NBLK_MAIN, 64, 0, stream>>>(ms, qt4, wsF, dv16, out);
}

// Round 4
// 276.637 us; speedup vs baseline: 1.3741x; 1.3741x over previous
//
#include <hip/hip_runtime.h>

#define WW 1024
#define HH 1024
#define NIMG 2
#define NCH 8
#define HWSZ (HH * WW)
#define CHW (NCH * HWSZ)
#define NBLK_MAIN 1024
// ws u32 layout: [0..2047] block mins, [2048..4095] block maxs,
// [4096] sum, [4097] cnt, [4098] ticket,
// dv16 (packed unorm16 mask diff) at 4352, u8 qt records at WS_QT.
#define WS_SUM 4096
#define WS_CNT 4097
#define WS_TKT 4098
#define WS_DV16 4352
#define WS_QT (4352 + HWSZ)
#define RECU4 320   // uint4 per (n,row,half) record: [p0 136][p1 136][pad 48]
#define SLOTU 1280  // u32 per LDS ring slot (= record size)

typedef unsigned int uint;

__device__ __forceinline__ uint pknorm(float a, float b) {
    uint d;
    asm("v_cvt_pknorm_u16_f32 %0, %1, %2" : "=v"(d) : "v"(a), "v"(b));
    return d;
}
__device__ __forceinline__ uint sadu8(uint a, uint b, uint c) {
    uint d;
    asm("v_sad_u8 %0, %1, %2, %3" : "=v"(d) : "v"(a), "v"(b), "v"(c));
    return d;
}
__device__ __forceinline__ uint q8(float x) {
    return (uint)__float2int_rn(x * 255.f);
}
__device__ __forceinline__ int reflect_idx(int t) {
    if (t < 0) t = -t;
    if (t > HH - 1) t = 2 * (HH - 1) - t;
    return t;
}
// padded granule (0..135) -> E/O slot (E first, then O)
__device__ __forceinline__ int gp2slot(int gp) {
    return (gp & 1) ? (68 + (gp >> 1)) : (gp >> 1);
}

#define GLD16(g, l)                                                         \
    __builtin_amdgcn_global_load_lds(                                       \
        (const __attribute__((address_space(1))) uint*)(g),                 \
        (__attribute__((address_space(3))) uint*)(l), 16, 0, 0)

// Fused pass 0+1. k_quant and k_mask are fully independent (disjoint in/out),
// each is latency-bound (~1 TB/s effective when run serially = 174us combined);
// one dispatch with 3-way interleaved block mapping overlaps their streams.
// b3 % 3 in {0,1} -> quant block qb = (b3/3)*2 + (b3%3)   (4096 blocks)
// b3 % 3 == 2     -> mask block  mb = b3/3                (2048 blocks)
__global__ __launch_bounds__(256) void k_pre(const float* __restrict__ tgt,
                                             uint4* __restrict__ qt4,
                                             const float* __restrict__ msO,
                                             const float* __restrict__ pan,
                                             float* __restrict__ wsF,
                                             uint* __restrict__ dv16) {
    const int b3 = blockIdx.x;
    const int m3 = b3 % 3;
    const int t = threadIdx.x;

    if (m3 != 2) {
        // ---------------- quant body (verbatim) ----------------
        int b = (b3 / 3) * 2 + m3;     // (n*2+p)*1024 + row
        int row = b & 1023;
        int np = b >> 10;
        int n = np >> 1, p = np & 1;
        const float* c0 = tgt + (size_t)(n * NCH + 4 * p) * HWSZ + (size_t)row * WW;

        float4 v0 = *(const float4*)(c0 + 4 * t);
        float4 v1 = *(const float4*)(c0 + HWSZ + 4 * t);
        float4 v2 = *(const float4*)(c0 + 2 * HWSZ + 4 * t);
        float4 v3 = *(const float4*)(c0 + 3 * HWSZ + 4 * t);
        uint4 u;
        u.x = q8(v0.x) | (q8(v1.x) << 8) | (q8(v2.x) << 16) | (q8(v3.x) << 24);
        u.y = q8(v0.y) | (q8(v1.y) << 8) | (q8(v2.y) << 16) | (q8(v3.y) << 24);
        u.z = q8(v0.z) | (q8(v1.z) << 8) | (q8(v2.z) << 16) | (q8(v3.z) << 24);
        u.w = q8(v0.w) | (q8(v1.w) << 8) | (q8(v2.w) << 16) | (q8(v3.w) << 24);

        size_t rb = ((size_t)((n << 10) + row)) * 2;
        int h1 = t >> 7;
        int gp = (t & 127) + 4;        // 4..131 within own half
        qt4[(rb + h1) * RECU4 + p * 136 + gp2slot(gp)] = u;
        // interior overlap granules (appear in the other half's halo region)
        if (t >= 124 && t < 128)
            qt4[(rb + 1) * RECU4 + p * 136 + gp2slot(t - 124)] = u;
        if (t >= 128 && t < 132)
            qt4[(rb + 0) * RECU4 + p * 136 + gp2slot(t - 128 + 132)] = u;
        // reflected edge halos: 32 scalar u32 (one px each)
        if (t < 32) {
            int which = t >> 4, m = t & 15;
            int pc = which ? (528 + m) : m;          // padded col
            int j = which ? (1022 - m) : (16 - m);   // reflected image col
            uint val = q8(c0[j]) | (q8(c0[j + HWSZ]) << 8) |
                       (q8(c0[j + 2 * HWSZ]) << 16) | (q8(c0[j + 3 * HWSZ]) << 24);
            uint* recU = (uint*)(qt4 + (rb + which) * RECU4);
            recU[p * 544 + gp2slot(pc >> 2) * 4 + (pc & 3)] = val;
        }
    } else {
        // ---------------- mask body (verbatim) ----------------
        int b = b3 / 3;
        int gid = b * 256 + t;
        int base = gid * 4;
        int n = base >> 20;
        int hw = base & (HWSZ - 1);
        const float* po = msO + (size_t)n * CHW + hw;
        float sx = 0.f, sy = 0.f, sz = 0.f, sw = 0.f;
#pragma unroll
        for (int c = 0; c < NCH; ++c) {
            float4 v = *(const float4*)(po + c * HWSZ);
            sx += v.x; sy += v.y; sz += v.z; sw += v.w;
        }
        float4 pv = *(const float4*)(pan + (size_t)n * HWSZ + hw);
        float4 d;
        d.x = fabsf(sx * 0.125f - pv.x);
        d.y = fabsf(sy * 0.125f - pv.y);
        d.z = fabsf(sz * 0.125f - pv.z);
        d.w = fabsf(sw * 0.125f - pv.w);
        uint2 dpk;
        dpk.x = pknorm(d.x, d.y);
        dpk.y = pknorm(d.z, d.w);
        *(uint2*)(dv16 + (base >> 1)) = dpk;

        float m = fminf(fminf(d.x, d.y), fminf(d.z, d.w));
        float M = fmaxf(fmaxf(d.x, d.y), fmaxf(d.z, d.w));
#pragma unroll
        for (int off = 32; off > 0; off >>= 1) {
            m = fminf(m, __shfl_down(m, off));
            M = fmaxf(M, __shfl_down(M, off));
        }
        __shared__ float sm[4], sM[4];
        int wid = t >> 6, lane = t & 63;
        if (lane == 0) { sm[wid] = m; sM[wid] = M; }
        __syncthreads();
        if (t == 0) {
            wsF[b] = fminf(fminf(sm[0], sm[1]), fminf(sm[2], sm[3]));
            wsF[2048 + b] = fmaxf(fmaxf(sM[0], sM[1]), fmaxf(sM[2], sM[3]));
            if (b == 0) {
                wsF[WS_SUM] = 0.f;
                wsF[WS_CNT] = 0.f;
                ((unsigned*)wsF)[WS_TKT] = 0u;
            }
        }
    }
}

// Pass 2: 1-wave block = half-row band (4 output rows, stride 4) over a 10-slot
// u8 DMA ring. Per di: 20-b128 burst into register windows; v_sad_u8 inner loop.
// REVERTED to the verified R0 codegen shape (132 VGPR, 98us): 64-thread block +
// 51.2 KB LDS keeps the backend's occupancy target at 1 wave/SIMD so the
// scheduler does NOT pressure-reduce the 20-load window burst (R1/R2/R3 all
// regressed to 64-76 VGPR / ~205us whenever target occupancy >= 3 waves/EU).
__global__ __launch_bounds__(64) void k_main(const float* __restrict__ ms,
                                             const uint4* __restrict__ qt4,
                                             float* __restrict__ wsF,
                                             const uint* __restrict__ dv16,
                                             float* __restrict__ out) {
    __shared__ __align__(16) uint ldsU[10 * SLOTU]; // 51.2 KB -> 3 blocks/CU
    const int t = threadIdx.x;        // 0..63
    const int b = blockIdx.x;         // 0..1023
    const int xcd = b & 7;
    const int q = b >> 3;             // 0..127
    const int n = q >> 6;
    const int r = q & 63;
    const int hb = r >> 5;
    const int w = r & 31;
    const int h0 = xcd * 128 + 16 * (w >> 2) + (w & 3);
    const int w0 = hb * 512 + 8 * t;

    // ---- mask min/max loads first (so their waitcnt doesn't drain stage DMA) ----
    float lmin = 1.0e38f, lmax = -1.0e38f;
#pragma unroll
    for (int k = 0; k < 8; ++k) {
        float4 v = ((const float4*)wsF)[k * 64 + t];
        float4 x = ((const float4*)(wsF + 2048))[k * 64 + t];
        lmin = fminf(lmin, fminf(fminf(v.x, v.y), fminf(v.z, v.w)));
        lmax = fmaxf(lmax, fmaxf(fmaxf(x.x, x.y), fmaxf(x.z, x.w)));
    }

    // ---- prologue: stage s=0..9 into ring slots 0..9 (5 GLD16 each) ----
    const size_t recStride2 = 2;      // records per row (halves)
    const size_t nBase = ((size_t)n << 10);
#pragma unroll 1
    for (int s = 0; s < 10; ++s) {
        int row = reflect_idx(h0 + 4 * (s - 4));
        const uint* rec = (const uint*)(qt4 + ((nBase + row) * recStride2 + hb) * RECU4);
#pragma unroll
        for (int c = 0; c < 5; ++c)
            GLD16(rec + c * 256 + 4 * t, &ldsU[s * SLOTU + c * 256]);
    }

#pragma unroll
    for (int off = 32; off > 0; off >>= 1) {
        lmin = fminf(lmin, __shfl_xor(lmin, off));
        lmax = fmaxf(lmax, __shfl_xor(lmax, off));
    }
    const float thresh = lmin + (lmax - lmin) * (10.0f / 255.0f);
    const float inv16 = 1.0f / 65535.0f;
    const float inv8 = 1.0f / 255.0f;

    asm volatile("s_waitcnt vmcnt(0)" ::: "memory");

    float lsum = 0.f, lcnt = 0.f;

#pragma unroll 1
    for (int k = 0; k < 4; ++k) {
        const int oh = h0 + 4 * k;

        // ms fragment: 8 px x 8 ch -> msq[2][8] (u8-packed), loads issued first
        const float* msBase = ms + (size_t)n * CHW + (size_t)oh * WW + w0;
        float4 A[2][4][2];
#pragma unroll
        for (int p = 0; p < 2; ++p)
#pragma unroll
            for (int cc = 0; cc < 4; ++cc) {
                A[p][cc][0] = *(const float4*)(msBase + (size_t)(4 * p + cc) * HWSZ);
                A[p][cc][1] = *(const float4*)(msBase + (size_t)(4 * p + cc) * HWSZ + 4);
            }
        uint4 dq = *(const uint4*)(dv16 + (((size_t)n * HWSZ + (size_t)oh * WW + w0) >> 1));

        // steady-state stage: row s=k+9 into dead slot k-1 (k=1,2)
        if (k == 1 || k == 2) {
            int prow = reflect_idx(h0 + 4 * (k + 5));
            const uint* rec = (const uint*)(qt4 + ((nBase + prow) * recStride2 + hb) * RECU4);
#pragma unroll
            for (int c = 0; c < 5; ++c)
                GLD16(rec + c * 256 + 4 * t, &ldsU[(k - 1) * SLOTU + c * 256]);
        }

        uint msq[2][8];
#pragma unroll
        for (int p = 0; p < 2; ++p) {
#pragma unroll
            for (int half = 0; half < 2; ++half) {
                float4 c0 = A[p][0][half], c1 = A[p][1][half],
                       c2 = A[p][2][half], c3 = A[p][3][half];
                msq[p][4 * half + 0] = q8(c0.x) | (q8(c1.x) << 8) | (q8(c2.x) << 16) | (q8(c3.x) << 24);
                msq[p][4 * half + 1] = q8(c0.y) | (q8(c1.y) << 8) | (q8(c2.y) << 16) | (q8(c3.y) << 24);
                msq[p][4 * half + 2] = q8(c0.z) | (q8(c1.z) << 8) | (q8(c2.z) << 16) | (q8(c3.z) << 24);
                msq[p][4 * half + 3] = q8(c0.w) | (q8(c1.w) << 8) | (q8(c2.w) << 16) | (q8(c3.w) << 24);
            }
        }

        uint minv[8];
#pragma unroll
        for (int p = 0; p < 8; ++p) minv[p] = 0xffffffffu;

#pragma unroll 1
        for (int di = 0; di < 9; ++di) {
            int slot = k + di; if (slot >= 10) slot -= 10;
            const uint* sb = &ldsU[slot * SLOTU];
            // 40-px windows, all reads independent (burst): E slots t..t+4, O likewise
            uint4 winE[2][5], winO[2][5];
#pragma unroll
            for (int p = 0; p < 2; ++p)
#pragma unroll
                for (int qq = 0; qq < 5; ++qq) {
                    winE[p][qq] = *(const uint4*)(sb + p * 544 + 4 * (t + qq));
                    winO[p][qq] = *(const uint4*)(sb + p * 544 + 272 + 4 * (t + qq));
                }
            uint acc[8];
#pragma unroll
            for (int dj = 0; dj < 9; ++dj) {
#pragma unroll
                for (int p = 0; p < 8; ++p) acc[p] = 0;
#pragma unroll
                for (int p = 0; p < 2; ++p) {
                    uint4 lo = (dj & 1) ? winO[p][(dj - 1) >> 1] : winE[p][dj >> 1];
                    uint4 hi = (dj & 1) ? winE[p][(dj + 1) >> 1] : winO[p][dj >> 1];
                    acc[0] = sadu8(msq[p][0], lo.x, acc[0]);
                    acc[1] = sadu8(msq[p][1], lo.y, acc[1]);
                    acc[2] = sadu8(msq[p][2], lo.z, acc[2]);
                    acc[3] = sadu8(msq[p][3], lo.w, acc[3]);
                    acc[4] = sadu8(msq[p][4], hi.x, acc[4]);
                    acc[5] = sadu8(msq[p][5], hi.y, acc[5]);
                    acc[6] = sadu8(msq[p][6], hi.z, acc[6]);
                    acc[7] = sadu8(msq[p][7], hi.w, acc[7]);
                }
#pragma unroll
                for (int p = 0; p < 8; ++p) minv[p] = min(minv[p], acc[p]);
            }
        }
        // drain the steady-state stage before next row reads its slot
        asm volatile("s_waitcnt vmcnt(0)" ::: "memory");

        // masked accumulate for this output row
        uint dw[4] = {dq.x, dq.y, dq.z, dq.w};
#pragma unroll
        for (int p = 0; p < 4; ++p) {
            float d0 = (float)(dw[p] & 0xffffu) * inv16;
            float d1 = (float)(dw[p] >> 16) * inv16;
            if (d0 > thresh) { lsum += (float)minv[2 * p] * inv8; lcnt += 1.f; }
            if (d1 > thresh) { lsum += (float)minv[2 * p + 1] * inv8; lcnt += 1.f; }
        }
    }

#pragma unroll
    for (int off = 32; off > 0; off >>= 1) {
        lsum += __shfl_down(lsum, off);
        lcnt += __shfl_down(lcnt, off);
    }
    if (t == 0) {
        atomicAdd(&wsF[WS_SUM], lsum);
        atomicAdd(&wsF[WS_CNT], lcnt);
        __threadfence();
        unsigned tk = atomicAdd((unsigned*)&wsF[WS_TKT], 1u);
        if (tk == NBLK_MAIN - 1) {
            float s = atomicAdd(&wsF[WS_SUM], 0.f);
            float c = atomicAdd(&wsF[WS_CNT], 0.f);
            out[0] = (c > 0.f) ? (s / fmaxf(c, 1.f)) : 0.f;
        }
    }
}

extern "C" void kernel_launch(void* const* d_in, const int* in_sizes, int n_in,
                              void* d_out, int out_size, void* d_ws, size_t ws_size,
                              hipStream_t stream) {
    const float* ms  = (const float*)d_in[0];
    const float* tgt = (const float*)d_in[1];
    const float* msO = (const float*)d_in[2];
    const float* pan = (const float*)d_in[3];
    float* out = (float*)d_out;
    float* wsF = (float*)d_ws;
    uint* dv16 = (uint*)d_ws + WS_DV16;
    uint4* qt4 = (uint4*)((uint*)d_ws + WS_QT);

    k_pre<<<6144, 256, 0, stream>>>(tgt, qt4, msO, pan, wsF, dv16);
    k_main<<<NBLK_MAIN, 64, 0, stream>>>(ms, qt4, wsF, dv16, out);
}